// Round 9
// baseline (906.330 us; speedup 1.0000x reference)
//
#include <hip/hip_runtime.h>
#include <math.h>

#define B_   64
#define MD   1024
#define H_   16
#define D_   64
#define LNEPS 1e-5f

// ---------------------------------------------------------------------------
// ws layout (floats):
//   q      [64][1024]
//   wtil   [64][16][1024]     w̃[b,h,m] = sum_d Wk[m, h*64+d] * q[b,h,d]
//   scores [64][16][sfull]
//   concat [64][1024]
//   integ  [64][1024]
//   fcwt   [1024][1024]       fc_weight transposed
// ---------------------------------------------------------------------------

__device__ __forceinline__ float waveMax(float v) {
    #pragma unroll
    for (int off = 32; off > 0; off >>= 1) v = fmaxf(v, __shfl_xor(v, off, 64));
    return v;
}
__device__ __forceinline__ float waveSum(float v) {
    #pragma unroll
    for (int off = 32; off > 0; off >>= 1) v += __shfl_xor(v, off, 64);
    return v;
}

// ---- Kernel A: q[b, col] = sum_m x[b, idx, m] * Wq[m, col] -----------------
// grid (4 col-chunks, 64 b), block 256
__global__ void k_q(const float* __restrict__ x, const float* __restrict__ wq,
                    const int* __restrict__ idxp, float* __restrict__ qout, int sfull) {
    const int tid = threadIdx.x;
    const int col = blockIdx.x * 256 + tid;
    const int b   = blockIdx.y;
    const int idx = *idxp;
    const float* xr = x + ((size_t)b * sfull + idx) * MD;   // uniform -> scalar loads
    float a0 = 0.f, a1 = 0.f, a2 = 0.f, a3 = 0.f;
    for (int m = 0; m < MD; m += 4) {
        a0 += xr[m]     * wq[(size_t)m * MD + col];
        a1 += xr[m + 1] * wq[(size_t)(m + 1) * MD + col];
        a2 += xr[m + 2] * wq[(size_t)(m + 2) * MD + col];
        a3 += xr[m + 3] * wq[(size_t)(m + 3) * MD + col];
    }
    qout[(size_t)b * MD + col] = (a0 + a1) + (a2 + a3);
}

// ---- Kernel B: wtil[b,h,m] = sum_d Wk[m, h*64+d] * q[b, h*64+d] ------------
// grid (16 h, 32 b-groups of 2), block 256
__global__ void k_wtil(const float* __restrict__ wk, const float* __restrict__ q,
                       float* __restrict__ wtil) {
    const int tid = threadIdx.x;
    const int h  = blockIdx.x;
    const int b0 = blockIdx.y * 2;
    for (int mi = 0; mi < 4; ++mi) {
        const int m = mi * 256 + tid;
        const float4* wrow = (const float4*)(wk + (size_t)m * MD + h * D_);
        float4 wv[16];
        #pragma unroll
        for (int j = 0; j < 16; ++j) wv[j] = wrow[j];
        #pragma unroll
        for (int bb = 0; bb < 2; ++bb) {
            const float* qh = q + (size_t)(b0 + bb) * MD + h * D_;  // uniform -> s_load
            float acc = 0.f;
            #pragma unroll
            for (int j = 0; j < 16; ++j)
                acc += wv[j].x * qh[4*j] + wv[j].y * qh[4*j+1]
                     + wv[j].z * qh[4*j+2] + wv[j].w * qh[4*j+3];
            wtil[((size_t)(b0 + bb) * H_ + h) * MD + m] = acc;
        }
    }
}

// ---- Kernel P1: scores[b,h,s] = (x[b,s,:] . wtil[b,h,:]) / 8 ---------------
// grid (64 b, sfull/512 s-tiles), block 256.
// v8 = v5 body with row pad 20 -> 17 floats: block LDS 45 -> 39.2 KB so
// 4 blocks/CU resident (16 waves, 4/SIMD; was 3/SIMD). Tests the TLP-
// starvation hypothesis for the ~130 us gap above the HBM floor.
// Bank check (pad 17, odd): X reads 17*sg mod 32 distinct (sg<16) with
// 4-way same-addr broadcast (free); W reads broadcast; writes <=2-way.
// Grid transposed so linear id = b + 64*sy -> XCD = b%8 (wtil L2-resident).
__global__ __launch_bounds__(256) void k_scores(
        const float* __restrict__ x, const float* __restrict__ wtil,
        const int* __restrict__ idxp, float* __restrict__ scores, int sfull) {
    __shared__ float Xw[4][128 * 17];  // per-wave: 128 rows x 16 m (+1 pad) = 8.5 KB
    __shared__ float Ww[4][16 * 17];   // per-wave: 16 h x 16 m (+1 pad) = 1.06 KB
    const int tid  = threadIdx.x;
    const int w    = tid >> 6;
    const int lane = tid & 63;
    const int sg   = lane & 15;      // s sub-index
    const int hg   = lane >> 4;      // h group
    const int b    = blockIdx.x;
    const int sblk = blockIdx.y * 512;
    const int s0   = sblk + w * 128; // this wave's first row
    const int S    = *idxp + 1;
    if (sblk >= S) return;

    const float* xb = x    + (size_t)b * sfull * MD;
    const float* wb = wtil + (size_t)b * H_ * MD;

    float* Xs = Xw[w];
    float* Ws = Ww[w];

    const int csl = lane >> 2;       // 0..15 staging row within group
    const int cf4 = lane & 3;        // 0..3 float4 slot

    float acc[8][4] = {};
    float4 nx[8];
    float4 nw;

#define ISSUE(MC) do {                                                         \
        _Pragma("unroll")                                                      \
        for (int i = 0; i < 8; ++i) {                                          \
            int sl = i * 16 + csl;                                             \
            int srow = s0 + sl;                                                \
            nx[i] = (srow < S)                                                 \
                ? *(const float4*)(xb + (size_t)srow * MD + (MC) + cf4 * 4)    \
                : make_float4(0.f, 0.f, 0.f, 0.f);                             \
        }                                                                      \
        nw = *(const float4*)(wb + (size_t)csl * MD + (MC) + cf4 * 4);         \
    } while (0)

    ISSUE(0);

    for (int mc = 0; mc < MD; mc += 16) {
        // commit staged regs to this wave's LDS slice (in-order after last
        // chunk's ds_reads; wave-private so no cross-wave hazard)
        #pragma unroll
        for (int i = 0; i < 8; ++i)
            *(float4*)(&Xs[(i * 16 + csl) * 17 + cf4 * 4]) = nx[i];
        *(float4*)(&Ws[csl * 17 + cf4 * 4]) = nw;

        if (mc + 16 < MD) ISSUE(mc + 16);   // prefetch next chunk into regs

        // compute 8s x 4h x 16m, in two 8-m halves to cap register pressure
        #pragma unroll
        for (int half = 0; half < 2; ++half) {
            float4 wrh[4][2];
            #pragma unroll
            for (int j = 0; j < 4; ++j) {
                #pragma unroll
                for (int mm = 0; mm < 2; ++mm)
                    wrh[j][mm] = *(const float4*)(&Ws[(hg + 4 * j) * 17 + (half * 2 + mm) * 4]);
            }
            #pragma unroll
            for (int k = 0; k < 8; ++k) {
                const float4 xr0 = *(const float4*)(&Xs[(sg + 16 * k) * 17 + (half * 2) * 4]);
                const float4 xr1 = *(const float4*)(&Xs[(sg + 16 * k) * 17 + (half * 2 + 1) * 4]);
                #pragma unroll
                for (int j = 0; j < 4; ++j) {
                    acc[k][j] += xr0.x * wrh[j][0].x + xr0.y * wrh[j][0].y
                               + xr0.z * wrh[j][0].z + xr0.w * wrh[j][0].w
                               + xr1.x * wrh[j][1].x + xr1.y * wrh[j][1].y
                               + xr1.z * wrh[j][1].z + xr1.w * wrh[j][1].w;
                }
            }
        }
    }
#undef ISSUE

    #pragma unroll
    for (int k = 0; k < 8; ++k) {
        const int s = s0 + sg + 16 * k;
        if (s < S) {
            #pragma unroll
            for (int j = 0; j < 4; ++j)
                scores[((size_t)b * H_ + (hg + 4 * j)) * sfull + s] = acc[k][j] * 0.125f;
        }
    }
}

// ---- Kernel C: softmax over s + sparse gather y = attn^T x + Wv projection -
// grid (16 h, 64 b), block 256
__global__ void k_attn(const float* __restrict__ x, const float* __restrict__ scores,
                       const float* __restrict__ wv, const int* __restrict__ idxp,
                       float* __restrict__ concat, int sfull) {
    __shared__ float red[8];
    __shared__ int   scanw[4];
    __shared__ int   lidx[4096];
    __shared__ float lw[4096];
    __shared__ float ylds[1024];
    __shared__ float pred[256];

    const int tid = threadIdx.x;
    const int h = blockIdx.x, b = blockIdx.y;
    const int S = *idxp + 1;
    const float* sc = scores + ((size_t)b * H_ + h) * sfull;

    float ls[16];
    float mx = -INFINITY;
    #pragma unroll
    for (int k = 0; k < 16; ++k) {
        int s = tid + 256 * k;
        if (s < S) { ls[k] = sc[s]; mx = fmaxf(mx, ls[k]); }
        else ls[k] = -INFINITY;
    }
    // block max
    mx = waveMax(mx);
    const int wid = tid >> 6, lane = tid & 63;
    if (lane == 0) red[wid] = mx;
    __syncthreads();
    mx = fmaxf(fmaxf(red[0], red[1]), fmaxf(red[2], red[3]));

    // denom + significant count (exp(s-max) <= 1.7e-15 contributes nothing)
    float sum = 0.f; int cnt = 0;
    #pragma unroll
    for (int k = 0; k < 16; ++k) {
        if (ls[k] > -INFINITY) {
            float e = ls[k] - mx;
            sum += expf(e);
            if (e > -34.f) ++cnt;
        }
    }
    sum = waveSum(sum);
    __syncthreads();
    if (lane == 0) red[4 + wid] = sum;
    __syncthreads();
    const float inv = 1.f / (red[4] + red[5] + red[6] + red[7]);

    // deterministic compaction: wave-level shfl scan + cross-wave LDS (1 barrier)
    int inc = cnt;
    #pragma unroll
    for (int off = 1; off < 64; off <<= 1) {
        int t = __shfl_up(inc, off, 64);
        if (lane >= off) inc += t;
    }
    if (lane == 63) scanw[wid] = inc;
    __syncthreads();
    int wbase = 0, total = 0;
    #pragma unroll
    for (int ww = 0; ww < 4; ++ww) {
        int t = scanw[ww];
        if (ww < wid) wbase += t;
        total += t;
    }
    int pos = wbase + inc - cnt;
    #pragma unroll
    for (int k = 0; k < 16; ++k) {
        if (ls[k] > -INFINITY) {
            float e = ls[k] - mx;
            if (e > -34.f) { lidx[pos] = tid + 256 * k; lw[pos] = expf(e) * inv; ++pos; }
        }
    }
    __syncthreads();

    // y[m] = sum_{significant s} attn * x[b,s,m]  (typically 1-3 rows)
    float4 acc = make_float4(0.f, 0.f, 0.f, 0.f);
    const float* xb = x + (size_t)b * sfull * MD;
    for (int e = 0; e < total; ++e) {
        int s = lidx[e]; float w = lw[e];
        float4 xv = *(const float4*)(xb + (size_t)s * MD + tid * 4);
        acc.x += w * xv.x; acc.y += w * xv.y; acc.z += w * xv.z; acc.w += w * xv.w;
    }
    *(float4*)(&ylds[tid * 4]) = acc;
    __syncthreads();

    // head_out[d] = sum_m y[m] * Wv[m, h*64+d]
    const int d = tid & 63, g = tid >> 6;
    const float* wcol = wv + (size_t)h * D_ + d;
    float part = 0.f;
    for (int m = g * 256; m < g * 256 + 256; ++m)
        part += ylds[m] * wcol[(size_t)m * MD];
    pred[tid] = part;
    __syncthreads();
    if (tid < 64) {
        float v = pred[tid] + pred[tid + 64] + pred[tid + 128] + pred[tid + 192];
        concat[(size_t)b * MD + h * D_ + tid] = v;
    }
}

// ---- Kernel T: fcwt[m][n] = fcW[n][m] --------------------------------------
__global__ void k_transpose(const float* __restrict__ a, float* __restrict__ at) {
    __shared__ float t[32][33];
    const int bx = blockIdx.x * 32, by = blockIdx.y * 32;
    const int tx = threadIdx.x & 31, ty = threadIdx.x >> 5;  // 32x8
    for (int r = ty; r < 32; r += 8)
        t[r][tx] = a[(size_t)(by + r) * MD + bx + tx];
    __syncthreads();
    for (int r = ty; r < 32; r += 8)
        at[(size_t)(bx + r) * MD + by + tx] = t[tx][r];
}

// ---- Kernel D: integ[b,n] = sum_m concat[b,m] * fcW[n,m] + bias[n] ---------
// grid (64 b, 16 n-chunks of 64), block 256: 4-way m-split + LDS reduce.
__global__ void k_fc(const float* __restrict__ concat, const float* __restrict__ fcwt,
                     const float* __restrict__ bias, float* __restrict__ integ) {
    __shared__ float c[1024];
    __shared__ float pred[256];
    const int tid = threadIdx.x, b = blockIdx.x;
    const int n0 = blockIdx.y * 64;
    const int nl = tid & 63, mg = tid >> 6;
    #pragma unroll
    for (int k = 0; k < 4; ++k) c[tid + 256 * k] = concat[(size_t)b * MD + tid + 256 * k];
    __syncthreads();
    const int mbase = mg * 256;
    float a0 = 0.f, a1 = 0.f, a2 = 0.f, a3 = 0.f;
    for (int m = 0; m < 256; m += 4) {
        a0 += c[mbase + m]     * fcwt[(size_t)(mbase + m) * MD + n0 + nl];
        a1 += c[mbase + m + 1] * fcwt[(size_t)(mbase + m + 1) * MD + n0 + nl];
        a2 += c[mbase + m + 2] * fcwt[(size_t)(mbase + m + 2) * MD + n0 + nl];
        a3 += c[mbase + m + 3] * fcwt[(size_t)(mbase + m + 3) * MD + n0 + nl];
    }
    pred[tid] = (a0 + a1) + (a2 + a3);
    __syncthreads();
    if (tid < 64)
        integ[(size_t)b * MD + n0 + tid] =
            pred[tid] + pred[tid + 64] + pred[tid + 128] + pred[tid + 192] + bias[n0 + tid];
}

// ---- Kernel E: LayerNorm ---------------------------------------------------
__global__ void k_ln(const float* __restrict__ integ, const float* __restrict__ gamma,
                     const float* __restrict__ beta, float* __restrict__ out) {
    __shared__ float red[8];
    const int tid = threadIdx.x, b = blockIdx.x;
    float v[4];
    #pragma unroll
    for (int k = 0; k < 4; ++k) v[k] = integ[(size_t)b * MD + tid + 256 * k];
    float s = v[0] + v[1] + v[2] + v[3];
    s = waveSum(s);
    const int wid = tid >> 6, lane = tid & 63;
    if (lane == 0) red[wid] = s;
    __syncthreads();
    const float mean = (red[0] + red[1] + red[2] + red[3]) * (1.f / MD);
    float q = 0.f;
    #pragma unroll
    for (int k = 0; k < 4; ++k) { float d = v[k] - mean; q += d * d; }
    q = waveSum(q);
    __syncthreads();
    if (lane == 0) red[4 + wid] = q;
    __syncthreads();
    const float var = (red[4] + red[5] + red[6] + red[7]) * (1.f / MD);
    const float rs = rsqrtf(var + LNEPS);
    #pragma unroll
    for (int k = 0; k < 4; ++k) {
        int i = tid + 256 * k;
        out[(size_t)b * MD + i] = (v[k] - mean) * rs * gamma[i] + beta[i];
    }
}

extern "C" void kernel_launch(void* const* d_in, const int* in_sizes, int n_in,
                              void* d_out, int out_size, void* d_ws, size_t ws_size,
                              hipStream_t stream) {
    const float* x     = (const float*)d_in[0];
    const float* wq    = (const float*)d_in[1];
    const float* wk    = (const float*)d_in[2];
    const float* wvp   = (const float*)d_in[3];
    const float* fcw   = (const float*)d_in[4];
    const float* fcb   = (const float*)d_in[5];
    const float* gamma = (const float*)d_in[6];
    const float* beta  = (const float*)d_in[7];
    const int*   idxp  = (const int*)d_in[8];
    float* out = (float*)d_out;

    const int sfull = in_sizes[0] / (B_ * MD);   // 4096

    float* q      = (float*)d_ws;
    float* wtil   = q      + (size_t)B_ * MD;
    float* scores = wtil   + (size_t)B_ * H_ * MD;
    float* concat = scores + (size_t)B_ * H_ * sfull;
    float* integ  = concat + (size_t)B_ * MD;
    float* fcwt   = integ  + (size_t)B_ * MD;

    hipLaunchKernelGGL(k_q,         dim3(4, 64),           dim3(256), 0, stream, x, wq, idxp, q, sfull);
    hipLaunchKernelGGL(k_wtil,      dim3(16, 32),          dim3(256), 0, stream, wk, q, wtil);
    hipLaunchKernelGGL(k_scores,    dim3(B_, (sfull + 511) / 512), dim3(256), 0, stream, x, wtil, idxp, scores, sfull);
    hipLaunchKernelGGL(k_transpose, dim3(32, 32),          dim3(256), 0, stream, fcw, fcwt);
    hipLaunchKernelGGL(k_attn,      dim3(H_, B_),          dim3(256), 0, stream, x, scores, wvp, idxp, concat, sfull);
    hipLaunchKernelGGL(k_fc,        dim3(64, 16),          dim3(256), 0, stream, concat, fcwt, fcb, integ);
    hipLaunchKernelGGL(k_ln,        dim3(B_),              dim3(256), 0, stream, integ, gamma, beta, out);
}

// Round 10
// 376.512 us; speedup vs baseline: 2.4072x; 2.4072x over previous
//
#include <hip/hip_runtime.h>
#include <math.h>

#define B_   64
#define MD   1024
#define H_   16
#define D_   64
#define LNEPS 1e-5f

// ---------------------------------------------------------------------------
// ws layout (floats):
//   q      [64][1024]
//   wtil   [64][16][1024]     w̃[b,h,m] = sum_d Wk[m, h*64+d] * q[b,h,d]
//   scores [64][16][sfull]
//   concat [64][1024]
//   integ  [64][1024]
//   fcwt   [1024][1024]       fc_weight transposed
// LESSON (R9): LDS row pad must be a multiple of 4 floats (16 B) or float4
// LDS ops lose b128 alignment and get split -> ~4x LDS instructions.
// ---------------------------------------------------------------------------

__device__ __forceinline__ float waveMax(float v) {
    #pragma unroll
    for (int off = 32; off > 0; off >>= 1) v = fmaxf(v, __shfl_xor(v, off, 64));
    return v;
}
__device__ __forceinline__ float waveSum(float v) {
    #pragma unroll
    for (int off = 32; off > 0; off >>= 1) v += __shfl_xor(v, off, 64);
    return v;
}

// ---- Kernel A: q[b, col] = sum_m x[b, idx, m] * Wq[m, col] -----------------
// grid (4 col-chunks, 64 b), block 256
__global__ void k_q(const float* __restrict__ x, const float* __restrict__ wq,
                    const int* __restrict__ idxp, float* __restrict__ qout, int sfull) {
    const int tid = threadIdx.x;
    const int col = blockIdx.x * 256 + tid;
    const int b   = blockIdx.y;
    const int idx = *idxp;
    const float* xr = x + ((size_t)b * sfull + idx) * MD;   // uniform -> scalar loads
    float a0 = 0.f, a1 = 0.f, a2 = 0.f, a3 = 0.f;
    for (int m = 0; m < MD; m += 4) {
        a0 += xr[m]     * wq[(size_t)m * MD + col];
        a1 += xr[m + 1] * wq[(size_t)(m + 1) * MD + col];
        a2 += xr[m + 2] * wq[(size_t)(m + 2) * MD + col];
        a3 += xr[m + 3] * wq[(size_t)(m + 3) * MD + col];
    }
    qout[(size_t)b * MD + col] = (a0 + a1) + (a2 + a3);
}

// ---- Kernel B: wtil[b,h,m] = sum_d Wk[m, h*64+d] * q[b, h*64+d] ------------
// grid (16 h, 32 b-groups of 2), block 256
__global__ void k_wtil(const float* __restrict__ wk, const float* __restrict__ q,
                       float* __restrict__ wtil) {
    const int tid = threadIdx.x;
    const int h  = blockIdx.x;
    const int b0 = blockIdx.y * 2;
    for (int mi = 0; mi < 4; ++mi) {
        const int m = mi * 256 + tid;
        const float4* wrow = (const float4*)(wk + (size_t)m * MD + h * D_);
        float4 wv[16];
        #pragma unroll
        for (int j = 0; j < 16; ++j) wv[j] = wrow[j];
        #pragma unroll
        for (int bb = 0; bb < 2; ++bb) {
            const float* qh = q + (size_t)(b0 + bb) * MD + h * D_;  // uniform -> s_load
            float acc = 0.f;
            #pragma unroll
            for (int j = 0; j < 16; ++j)
                acc += wv[j].x * qh[4*j] + wv[j].y * qh[4*j+1]
                     + wv[j].z * qh[4*j+2] + wv[j].w * qh[4*j+3];
            wtil[((size_t)(b0 + bb) * H_ + h) * MD + m] = acc;
        }
    }
}

// ---- Kernel P1: scores[b,h,s] = (x[b,s,:] . wtil[b,h,:]) / 8 ---------------
// grid (64 b, sfull/512 s-tiles), block 256.
// v9 = R8 structure (pad 20 restored) + DEPTH-2 register prefetch: two named
// buffers (nxA/nxB, static indexing) so loads for chunk k+2 are issued during
// chunk k's compute -- ~2 compute-phases of vmcnt slack to cover the per-CU
// HBM queuing delay (~3 us/epoch with 8 waves/CU) that depth-1 couldn't hide.
// Wave-private LDS, zero barriers, k=8 rows/thread, 16-col chunks.
// Grid transposed so linear id = b + 64*sy -> XCD = b%8 (wtil L2-resident).
__global__ __launch_bounds__(256) void k_scores(
        const float* __restrict__ x, const float* __restrict__ wtil,
        const int* __restrict__ idxp, float* __restrict__ scores, int sfull) {
    __shared__ float Xw[4][128 * 20];  // per-wave: 128 rows x 16 m (+4 pad) = 10 KB
    __shared__ float Ww[4][16 * 20];   // per-wave: 16 h x 16 m (+4 pad) = 1.25 KB
    const int tid  = threadIdx.x;
    const int w    = tid >> 6;
    const int lane = tid & 63;
    const int sg   = lane & 15;      // s sub-index
    const int hg   = lane >> 4;      // h group
    const int b    = blockIdx.x;
    const int sblk = blockIdx.y * 512;
    const int s0   = sblk + w * 128; // this wave's first row
    const int S    = *idxp + 1;
    if (sblk >= S) return;

    const float* xb = x    + (size_t)b * sfull * MD;
    const float* wb = wtil + (size_t)b * H_ * MD;

    float* Xs = Xw[w];
    float* Ws = Ww[w];

    const int csl = lane >> 2;       // 0..15 staging row within group
    const int cf4 = lane & 3;        // 0..3 float4 slot

    float acc[8][4] = {};
    float4 nxA[8], nxB[8];
    float4 nwA, nwB;

#define ISSUE(NX, NW, MC) do {                                                 \
        _Pragma("unroll")                                                      \
        for (int i = 0; i < 8; ++i) {                                          \
            int sl = i * 16 + csl;                                             \
            int srow = s0 + sl;                                                \
            NX[i] = (srow < S)                                                 \
                ? *(const float4*)(xb + (size_t)srow * MD + (MC) + cf4 * 4)    \
                : make_float4(0.f, 0.f, 0.f, 0.f);                             \
        }                                                                      \
        NW = *(const float4*)(wb + (size_t)csl * MD + (MC) + cf4 * 4);         \
    } while (0)

#define COMMIT(NX, NW) do {                                                    \
        _Pragma("unroll")                                                      \
        for (int i = 0; i < 8; ++i)                                            \
            *(float4*)(&Xs[(i * 16 + csl) * 20 + cf4 * 4]) = NX[i];            \
        *(float4*)(&Ws[csl * 20 + cf4 * 4]) = NW;                              \
    } while (0)

#define COMPUTE() do {                                                         \
        _Pragma("unroll")                                                      \
        for (int half = 0; half < 2; ++half) {                                 \
            float4 wrh[4][2];                                                  \
            _Pragma("unroll")                                                  \
            for (int j = 0; j < 4; ++j) {                                      \
                _Pragma("unroll")                                              \
                for (int mm = 0; mm < 2; ++mm)                                 \
                    wrh[j][mm] = *(const float4*)(&Ws[(hg + 4 * j) * 20 + (half * 2 + mm) * 4]); \
            }                                                                  \
            _Pragma("unroll")                                                  \
            for (int k = 0; k < 8; ++k) {                                      \
                const float4 xr0 = *(const float4*)(&Xs[(sg + 16 * k) * 20 + (half * 2) * 4]); \
                const float4 xr1 = *(const float4*)(&Xs[(sg + 16 * k) * 20 + (half * 2 + 1) * 4]); \
                _Pragma("unroll")                                              \
                for (int j = 0; j < 4; ++j) {                                  \
                    acc[k][j] += xr0.x * wrh[j][0].x + xr0.y * wrh[j][0].y     \
                               + xr0.z * wrh[j][0].z + xr0.w * wrh[j][0].w     \
                               + xr1.x * wrh[j][1].x + xr1.y * wrh[j][1].y     \
                               + xr1.z * wrh[j][1].z + xr1.w * wrh[j][1].w;    \
                }                                                              \
            }                                                                  \
        }                                                                      \
    } while (0)

    ISSUE(nxA, nwA, 0);
    ISSUE(nxB, nwB, 16);

    for (int mc = 0; mc < MD; mc += 32) {
        COMMIT(nxA, nwA);
        if (mc + 32 < MD) ISSUE(nxA, nwA, mc + 32);
        COMPUTE();                                  // chunk mc

        COMMIT(nxB, nwB);
        if (mc + 48 < MD) ISSUE(nxB, nwB, mc + 48);
        COMPUTE();                                  // chunk mc+16
    }
#undef ISSUE
#undef COMMIT
#undef COMPUTE

    #pragma unroll
    for (int k = 0; k < 8; ++k) {
        const int s = s0 + sg + 16 * k;
        if (s < S) {
            #pragma unroll
            for (int j = 0; j < 4; ++j)
                scores[((size_t)b * H_ + (hg + 4 * j)) * sfull + s] = acc[k][j] * 0.125f;
        }
    }
}

// ---- Kernel C: softmax over s + sparse gather y = attn^T x + Wv projection -
// grid (16 h, 64 b), block 256
__global__ void k_attn(const float* __restrict__ x, const float* __restrict__ scores,
                       const float* __restrict__ wv, const int* __restrict__ idxp,
                       float* __restrict__ concat, int sfull) {
    __shared__ float red[8];
    __shared__ int   scanw[4];
    __shared__ int   lidx[4096];
    __shared__ float lw[4096];
    __shared__ float ylds[1024];
    __shared__ float pred[256];

    const int tid = threadIdx.x;
    const int h = blockIdx.x, b = blockIdx.y;
    const int S = *idxp + 1;
    const float* sc = scores + ((size_t)b * H_ + h) * sfull;

    float ls[16];
    float mx = -INFINITY;
    #pragma unroll
    for (int k = 0; k < 16; ++k) {
        int s = tid + 256 * k;
        if (s < S) { ls[k] = sc[s]; mx = fmaxf(mx, ls[k]); }
        else ls[k] = -INFINITY;
    }
    // block max
    mx = waveMax(mx);
    const int wid = tid >> 6, lane = tid & 63;
    if (lane == 0) red[wid] = mx;
    __syncthreads();
    mx = fmaxf(fmaxf(red[0], red[1]), fmaxf(red[2], red[3]));

    // denom + significant count (exp(s-max) <= 1.7e-15 contributes nothing)
    float sum = 0.f; int cnt = 0;
    #pragma unroll
    for (int k = 0; k < 16; ++k) {
        if (ls[k] > -INFINITY) {
            float e = ls[k] - mx;
            sum += expf(e);
            if (e > -34.f) ++cnt;
        }
    }
    sum = waveSum(sum);
    __syncthreads();
    if (lane == 0) red[4 + wid] = sum;
    __syncthreads();
    const float inv = 1.f / (red[4] + red[5] + red[6] + red[7]);

    // deterministic compaction: wave-level shfl scan + cross-wave LDS (1 barrier)
    int inc = cnt;
    #pragma unroll
    for (int off = 1; off < 64; off <<= 1) {
        int t = __shfl_up(inc, off, 64);
        if (lane >= off) inc += t;
    }
    if (lane == 63) scanw[wid] = inc;
    __syncthreads();
    int wbase = 0, total = 0;
    #pragma unroll
    for (int ww = 0; ww < 4; ++ww) {
        int t = scanw[ww];
        if (ww < wid) wbase += t;
        total += t;
    }
    int pos = wbase + inc - cnt;
    #pragma unroll
    for (int k = 0; k < 16; ++k) {
        if (ls[k] > -INFINITY) {
            float e = ls[k] - mx;
            if (e > -34.f) { lidx[pos] = tid + 256 * k; lw[pos] = expf(e) * inv; ++pos; }
        }
    }
    __syncthreads();

    // y[m] = sum_{significant s} attn * x[b,s,m]  (typically 1-3 rows)
    float4 acc = make_float4(0.f, 0.f, 0.f, 0.f);
    const float* xb = x + (size_t)b * sfull * MD;
    for (int e = 0; e < total; ++e) {
        int s = lidx[e]; float w = lw[e];
        float4 xv = *(const float4*)(xb + (size_t)s * MD + tid * 4);
        acc.x += w * xv.x; acc.y += w * xv.y; acc.z += w * xv.z; acc.w += w * xv.w;
    }
    *(float4*)(&ylds[tid * 4]) = acc;
    __syncthreads();

    // head_out[d] = sum_m y[m] * Wv[m, h*64+d]
    const int d = tid & 63, g = tid >> 6;
    const float* wcol = wv + (size_t)h * D_ + d;
    float part = 0.f;
    for (int m = g * 256; m < g * 256 + 256; ++m)
        part += ylds[m] * wcol[(size_t)m * MD];
    pred[tid] = part;
    __syncthreads();
    if (tid < 64) {
        float v = pred[tid] + pred[tid + 64] + pred[tid + 128] + pred[tid + 192];
        concat[(size_t)b * MD + h * D_ + tid] = v;
    }
}

// ---- Kernel T: fcwt[m][n] = fcW[n][m] --------------------------------------
__global__ void k_transpose(const float* __restrict__ a, float* __restrict__ at) {
    __shared__ float t[32][33];
    const int bx = blockIdx.x * 32, by = blockIdx.y * 32;
    const int tx = threadIdx.x & 31, ty = threadIdx.x >> 5;  // 32x8
    for (int r = ty; r < 32; r += 8)
        t[r][tx] = a[(size_t)(by + r) * MD + bx + tx];
    __syncthreads();
    for (int r = ty; r < 32; r += 8)
        at[(size_t)(bx + r) * MD + by + tx] = t[tx][r];
}

// ---- Kernel D: integ[b,n] = sum_m concat[b,m] * fcW[n,m] + bias[n] ---------
// grid (64 b, 16 n-chunks of 64), block 256: 4-way m-split + LDS reduce.
__global__ void k_fc(const float* __restrict__ concat, const float* __restrict__ fcwt,
                     const float* __restrict__ bias, float* __restrict__ integ) {
    __shared__ float c[1024];
    __shared__ float pred[256];
    const int tid = threadIdx.x, b = blockIdx.x;
    const int n0 = blockIdx.y * 64;
    const int nl = tid & 63, mg = tid >> 6;
    #pragma unroll
    for (int k = 0; k < 4; ++k) c[tid + 256 * k] = concat[(size_t)b * MD + tid + 256 * k];
    __syncthreads();
    const int mbase = mg * 256;
    float a0 = 0.f, a1 = 0.f, a2 = 0.f, a3 = 0.f;
    for (int m = 0; m < 256; m += 4) {
        a0 += c[mbase + m]     * fcwt[(size_t)(mbase + m) * MD + n0 + nl];
        a1 += c[mbase + m + 1] * fcwt[(size_t)(mbase + m + 1) * MD + n0 + nl];
        a2 += c[mbase + m + 2] * fcwt[(size_t)(mbase + m + 2) * MD + n0 + nl];
        a3 += c[mbase + m + 3] * fcwt[(size_t)(mbase + m + 3) * MD + n0 + nl];
    }
    pred[tid] = (a0 + a1) + (a2 + a3);
    __syncthreads();
    if (tid < 64)
        integ[(size_t)b * MD + n0 + tid] =
            pred[tid] + pred[tid + 64] + pred[tid + 128] + pred[tid + 192] + bias[n0 + tid];
}

// ---- Kernel E: LayerNorm ---------------------------------------------------
__global__ void k_ln(const float* __restrict__ integ, const float* __restrict__ gamma,
                     const float* __restrict__ beta, float* __restrict__ out) {
    __shared__ float red[8];
    const int tid = threadIdx.x, b = blockIdx.x;
    float v[4];
    #pragma unroll
    for (int k = 0; k < 4; ++k) v[k] = integ[(size_t)b * MD + tid + 256 * k];
    float s = v[0] + v[1] + v[2] + v[3];
    s = waveSum(s);
    const int wid = tid >> 6, lane = tid & 63;
    if (lane == 0) red[wid] = s;
    __syncthreads();
    const float mean = (red[0] + red[1] + red[2] + red[3]) * (1.f / MD);
    float q = 0.f;
    #pragma unroll
    for (int k = 0; k < 4; ++k) { float d = v[k] - mean; q += d * d; }
    q = waveSum(q);
    __syncthreads();
    if (lane == 0) red[4 + wid] = q;
    __syncthreads();
    const float var = (red[4] + red[5] + red[6] + red[7]) * (1.f / MD);
    const float rs = rsqrtf(var + LNEPS);
    #pragma unroll
    for (int k = 0; k < 4; ++k) {
        int i = tid + 256 * k;
        out[(size_t)b * MD + i] = (v[k] - mean) * rs * gamma[i] + beta[i];
    }
}

extern "C" void kernel_launch(void* const* d_in, const int* in_sizes, int n_in,
                              void* d_out, int out_size, void* d_ws, size_t ws_size,
                              hipStream_t stream) {
    const float* x     = (const float*)d_in[0];
    const float* wq    = (const float*)d_in[1];
    const float* wk    = (const float*)d_in[2];
    const float* wvp   = (const float*)d_in[3];
    const float* fcw   = (const float*)d_in[4];
    const float* fcb   = (const float*)d_in[5];
    const float* gamma = (const float*)d_in[6];
    const float* beta  = (const float*)d_in[7];
    const int*   idxp  = (const int*)d_in[8];
    float* out = (float*)d_out;

    const int sfull = in_sizes[0] / (B_ * MD);   // 4096

    float* q      = (float*)d_ws;
    float* wtil   = q      + (size_t)B_ * MD;
    float* scores = wtil   + (size_t)B_ * H_ * MD;
    float* concat = scores + (size_t)B_ * H_ * sfull;
    float* integ  = concat + (size_t)B_ * MD;
    float* fcwt   = integ  + (size_t)B_ * MD;

    hipLaunchKernelGGL(k_q,         dim3(4, 64),           dim3(256), 0, stream, x, wq, idxp, q, sfull);
    hipLaunchKernelGGL(k_wtil,      dim3(16, 32),          dim3(256), 0, stream, wk, q, wtil);
    hipLaunchKernelGGL(k_scores,    dim3(B_, (sfull + 511) / 512), dim3(256), 0, stream, x, wtil, idxp, scores, sfull);
    hipLaunchKernelGGL(k_transpose, dim3(32, 32),          dim3(256), 0, stream, fcw, fcwt);
    hipLaunchKernelGGL(k_attn,      dim3(H_, B_),          dim3(256), 0, stream, x, scores, wvp, idxp, concat, sfull);
    hipLaunchKernelGGL(k_fc,        dim3(64, 16),          dim3(256), 0, stream, concat, fcwt, fcb, integ);
    hipLaunchKernelGGL(k_ln,        dim3(B_),              dim3(256), 0, stream, integ, gamma, beta, out);
}

// Round 11
// 345.646 us; speedup vs baseline: 2.6221x; 1.0893x over previous
//
#include <hip/hip_runtime.h>
#include <math.h>

#define B_   64
#define MD   1024
#define H_   16
#define D_   64
#define LNEPS 1e-5f

// ---------------------------------------------------------------------------
// ws layout (floats):
//   q      [64][1024]
//   wtil   [64][16][1024]     w̃[b,h,m] = sum_d Wk[m, h*64+d] * q[b,h,d]
//   scores [64][16][sfull]
//   concat [64][1024]
//   integ  [64][1024]
//   fcwt   [1024][1024]       fc_weight transposed
// LESSON (R9): LDS row pad must be a multiple of 4 floats (16 B) or float4
// LDS ops lose b128 alignment and get split -> ~4x LDS instructions.
// LESSON (R10): depth-2 reg prefetch regressed; latency depth is not the
// k_scores binder. Testing DRAM channel-resonance theory this round.
// ---------------------------------------------------------------------------

__device__ __forceinline__ float waveMax(float v) {
    #pragma unroll
    for (int off = 32; off > 0; off >>= 1) v = fmaxf(v, __shfl_xor(v, off, 64));
    return v;
}
__device__ __forceinline__ float waveSum(float v) {
    #pragma unroll
    for (int off = 32; off > 0; off >>= 1) v += __shfl_xor(v, off, 64);
    return v;
}

// ---- Kernel A: q[b, col] = sum_m x[b, idx, m] * Wq[m, col] -----------------
// grid (4 col-chunks, 64 b), block 256
__global__ void k_q(const float* __restrict__ x, const float* __restrict__ wq,
                    const int* __restrict__ idxp, float* __restrict__ qout, int sfull) {
    const int tid = threadIdx.x;
    const int col = blockIdx.x * 256 + tid;
    const int b   = blockIdx.y;
    const int idx = *idxp;
    const float* xr = x + ((size_t)b * sfull + idx) * MD;   // uniform -> scalar loads
    float a0 = 0.f, a1 = 0.f, a2 = 0.f, a3 = 0.f;
    for (int m = 0; m < MD; m += 4) {
        a0 += xr[m]     * wq[(size_t)m * MD + col];
        a1 += xr[m + 1] * wq[(size_t)(m + 1) * MD + col];
        a2 += xr[m + 2] * wq[(size_t)(m + 2) * MD + col];
        a3 += xr[m + 3] * wq[(size_t)(m + 3) * MD + col];
    }
    qout[(size_t)b * MD + col] = (a0 + a1) + (a2 + a3);
}

// ---- Kernel B: wtil[b,h,m] = sum_d Wk[m, h*64+d] * q[b, h*64+d] ------------
// grid (16 h, 32 b-groups of 2), block 256
__global__ void k_wtil(const float* __restrict__ wk, const float* __restrict__ q,
                       float* __restrict__ wtil) {
    const int tid = threadIdx.x;
    const int h  = blockIdx.x;
    const int b0 = blockIdx.y * 2;
    for (int mi = 0; mi < 4; ++mi) {
        const int m = mi * 256 + tid;
        const float4* wrow = (const float4*)(wk + (size_t)m * MD + h * D_);
        float4 wv[16];
        #pragma unroll
        for (int j = 0; j < 16; ++j) wv[j] = wrow[j];
        #pragma unroll
        for (int bb = 0; bb < 2; ++bb) {
            const float* qh = q + (size_t)(b0 + bb) * MD + h * D_;  // uniform -> s_load
            float acc = 0.f;
            #pragma unroll
            for (int j = 0; j < 16; ++j)
                acc += wv[j].x * qh[4*j] + wv[j].y * qh[4*j+1]
                     + wv[j].z * qh[4*j+2] + wv[j].w * qh[4*j+3];
            wtil[((size_t)(b0 + bb) * H_ + h) * MD + m] = acc;
        }
    }
}

// ---- Kernel P1: scores[b,h,s] = (x[b,s,:] . wtil[b,h,:]) / 8 ---------------
// grid (64 b, sfull/512 s-tiles), block 256.
// v10 = R8 body (v5, pad 20, depth-1) + PER-WAVE M-PHASE STAGGER.
// Theory: x rows are 4096 B apart; with all waves marching mc in lockstep
// the whole chip requests a 4-KB-stride address set whose channel bits are
// constant -> only a fraction of HBM channels active at once (~3 TB/s cap,
// invariant to every SM-side change tried in R4..R10). Staggering each
// wave's chunk ring start spreads instantaneous requests over all 64 column
// positions -> all channels. Accumulation order change is fp32-noise only.
__global__ __launch_bounds__(256) void k_scores(
        const float* __restrict__ x, const float* __restrict__ wtil,
        const int* __restrict__ idxp, float* __restrict__ scores, int sfull) {
    __shared__ float Xw[4][128 * 20];  // per-wave: 128 rows x 16 m (+4 pad) = 10 KB
    __shared__ float Ww[4][16 * 20];   // per-wave: 16 h x 16 m (+4 pad) = 1.25 KB
    const int tid  = threadIdx.x;
    const int w    = tid >> 6;
    const int lane = tid & 63;
    const int sg   = lane & 15;      // s sub-index
    const int hg   = lane >> 4;      // h group
    const int b    = blockIdx.x;
    const int sblk = blockIdx.y * 512;
    const int s0   = sblk + w * 128; // this wave's first row
    const int S    = *idxp + 1;
    if (sblk >= S) return;

    const float* xb = x    + (size_t)b * sfull * MD;
    const float* wb = wtil + (size_t)b * H_ * MD;

    float* Xs = Xw[w];
    float* Ws = Ww[w];

    const int csl = lane >> 2;       // 0..15 staging row within group
    const int cf4 = lane & 3;        // 0..3 float4 slot

    // per-wave chunk-ring phase: decorrelate HBM channel usage
    const int phase = (b + blockIdx.y * 8 + w * 16) & 63;
#define MCOF(T) (((((T) + phase) & 63)) * 16)

    float acc[8][4] = {};
    float4 nx[8];
    float4 nw;

#define ISSUE(MC) do {                                                         \
        _Pragma("unroll")                                                      \
        for (int i = 0; i < 8; ++i) {                                          \
            int sl = i * 16 + csl;                                             \
            int srow = s0 + sl;                                                \
            nx[i] = (srow < S)                                                 \
                ? *(const float4*)(xb + (size_t)srow * MD + (MC) + cf4 * 4)    \
                : make_float4(0.f, 0.f, 0.f, 0.f);                             \
        }                                                                      \
        nw = *(const float4*)(wb + (size_t)csl * MD + (MC) + cf4 * 4);         \
    } while (0)

    ISSUE(MCOF(0));

    for (int t = 0; t < 64; ++t) {
        // commit staged regs to this wave's LDS slice (in-order after last
        // chunk's ds_reads; wave-private so no cross-wave hazard)
        #pragma unroll
        for (int i = 0; i < 8; ++i)
            *(float4*)(&Xs[(i * 16 + csl) * 20 + cf4 * 4]) = nx[i];
        *(float4*)(&Ws[csl * 20 + cf4 * 4]) = nw;

        if (t + 1 < 64) ISSUE(MCOF(t + 1));   // prefetch next ring chunk

        // compute 8s x 4h x 16m, in two 8-m halves to cap register pressure
        #pragma unroll
        for (int half = 0; half < 2; ++half) {
            float4 wrh[4][2];
            #pragma unroll
            for (int j = 0; j < 4; ++j) {
                #pragma unroll
                for (int mm = 0; mm < 2; ++mm)
                    wrh[j][mm] = *(const float4*)(&Ws[(hg + 4 * j) * 20 + (half * 2 + mm) * 4]);
            }
            #pragma unroll
            for (int k = 0; k < 8; ++k) {
                const float4 xr0 = *(const float4*)(&Xs[(sg + 16 * k) * 20 + (half * 2) * 4]);
                const float4 xr1 = *(const float4*)(&Xs[(sg + 16 * k) * 20 + (half * 2 + 1) * 4]);
                #pragma unroll
                for (int j = 0; j < 4; ++j) {
                    acc[k][j] += xr0.x * wrh[j][0].x + xr0.y * wrh[j][0].y
                               + xr0.z * wrh[j][0].z + xr0.w * wrh[j][0].w
                               + xr1.x * wrh[j][1].x + xr1.y * wrh[j][1].y
                               + xr1.z * wrh[j][1].z + xr1.w * wrh[j][1].w;
                }
            }
        }
    }
#undef ISSUE
#undef MCOF

    #pragma unroll
    for (int k = 0; k < 8; ++k) {
        const int s = s0 + sg + 16 * k;
        if (s < S) {
            #pragma unroll
            for (int j = 0; j < 4; ++j)
                scores[((size_t)b * H_ + (hg + 4 * j)) * sfull + s] = acc[k][j] * 0.125f;
        }
    }
}

// ---- Kernel C: softmax over s + sparse gather y = attn^T x + Wv projection -
// grid (16 h, 64 b), block 256
__global__ void k_attn(const float* __restrict__ x, const float* __restrict__ scores,
                       const float* __restrict__ wv, const int* __restrict__ idxp,
                       float* __restrict__ concat, int sfull) {
    __shared__ float red[8];
    __shared__ int   scanw[4];
    __shared__ int   lidx[4096];
    __shared__ float lw[4096];
    __shared__ float ylds[1024];
    __shared__ float pred[256];

    const int tid = threadIdx.x;
    const int h = blockIdx.x, b = blockIdx.y;
    const int S = *idxp + 1;
    const float* sc = scores + ((size_t)b * H_ + h) * sfull;

    float ls[16];
    float mx = -INFINITY;
    #pragma unroll
    for (int k = 0; k < 16; ++k) {
        int s = tid + 256 * k;
        if (s < S) { ls[k] = sc[s]; mx = fmaxf(mx, ls[k]); }
        else ls[k] = -INFINITY;
    }
    // block max
    mx = waveMax(mx);
    const int wid = tid >> 6, lane = tid & 63;
    if (lane == 0) red[wid] = mx;
    __syncthreads();
    mx = fmaxf(fmaxf(red[0], red[1]), fmaxf(red[2], red[3]));

    // denom + significant count (exp(s-max) <= 1.7e-15 contributes nothing)
    float sum = 0.f; int cnt = 0;
    #pragma unroll
    for (int k = 0; k < 16; ++k) {
        if (ls[k] > -INFINITY) {
            float e = ls[k] - mx;
            sum += expf(e);
            if (e > -34.f) ++cnt;
        }
    }
    sum = waveSum(sum);
    __syncthreads();
    if (lane == 0) red[4 + wid] = sum;
    __syncthreads();
    const float inv = 1.f / (red[4] + red[5] + red[6] + red[7]);

    // deterministic compaction: wave-level shfl scan + cross-wave LDS (1 barrier)
    int inc = cnt;
    #pragma unroll
    for (int off = 1; off < 64; off <<= 1) {
        int t = __shfl_up(inc, off, 64);
        if (lane >= off) inc += t;
    }
    if (lane == 63) scanw[wid] = inc;
    __syncthreads();
    int wbase = 0, total = 0;
    #pragma unroll
    for (int ww = 0; ww < 4; ++ww) {
        int t = scanw[ww];
        if (ww < wid) wbase += t;
        total += t;
    }
    int pos = wbase + inc - cnt;
    #pragma unroll
    for (int k = 0; k < 16; ++k) {
        if (ls[k] > -INFINITY) {
            float e = ls[k] - mx;
            if (e > -34.f) { lidx[pos] = tid + 256 * k; lw[pos] = expf(e) * inv; ++pos; }
        }
    }
    __syncthreads();

    // y[m] = sum_{significant s} attn * x[b,s,m]  (typically 1-3 rows)
    float4 acc = make_float4(0.f, 0.f, 0.f, 0.f);
    const float* xb = x + (size_t)b * sfull * MD;
    for (int e = 0; e < total; ++e) {
        int s = lidx[e]; float w = lw[e];
        float4 xv = *(const float4*)(xb + (size_t)s * MD + tid * 4);
        acc.x += w * xv.x; acc.y += w * xv.y; acc.z += w * xv.z; acc.w += w * xv.w;
    }
    *(float4*)(&ylds[tid * 4]) = acc;
    __syncthreads();

    // head_out[d] = sum_m y[m] * Wv[m, h*64+d]
    const int d = tid & 63, g = tid >> 6;
    const float* wcol = wv + (size_t)h * D_ + d;
    float part = 0.f;
    for (int m = g * 256; m < g * 256 + 256; ++m)
        part += ylds[m] * wcol[(size_t)m * MD];
    pred[tid] = part;
    __syncthreads();
    if (tid < 64) {
        float v = pred[tid] + pred[tid + 64] + pred[tid + 128] + pred[tid + 192];
        concat[(size_t)b * MD + h * D_ + tid] = v;
    }
}

// ---- Kernel T: fcwt[m][n] = fcW[n][m] --------------------------------------
__global__ void k_transpose(const float* __restrict__ a, float* __restrict__ at) {
    __shared__ float t[32][33];
    const int bx = blockIdx.x * 32, by = blockIdx.y * 32;
    const int tx = threadIdx.x & 31, ty = threadIdx.x >> 5;  // 32x8
    for (int r = ty; r < 32; r += 8)
        t[r][tx] = a[(size_t)(by + r) * MD + bx + tx];
    __syncthreads();
    for (int r = ty; r < 32; r += 8)
        at[(size_t)(bx + r) * MD + by + tx] = t[tx][r];
}

// ---- Kernel D: integ[b,n] = sum_m concat[b,m] * fcW[n,m] + bias[n] ---------
// grid (64 b, 16 n-chunks of 64), block 256: 4-way m-split + LDS reduce.
__global__ void k_fc(const float* __restrict__ concat, const float* __restrict__ fcwt,
                     const float* __restrict__ bias, float* __restrict__ integ) {
    __shared__ float c[1024];
    __shared__ float pred[256];
    const int tid = threadIdx.x, b = blockIdx.x;
    const int n0 = blockIdx.y * 64;
    const int nl = tid & 63, mg = tid >> 6;
    #pragma unroll
    for (int k = 0; k < 4; ++k) c[tid + 256 * k] = concat[(size_t)b * MD + tid + 256 * k];
    __syncthreads();
    const int mbase = mg * 256;
    float a0 = 0.f, a1 = 0.f, a2 = 0.f, a3 = 0.f;
    for (int m = 0; m < 256; m += 4) {
        a0 += c[mbase + m]     * fcwt[(size_t)(mbase + m) * MD + n0 + nl];
        a1 += c[mbase + m + 1] * fcwt[(size_t)(mbase + m + 1) * MD + n0 + nl];
        a2 += c[mbase + m + 2] * fcwt[(size_t)(mbase + m + 2) * MD + n0 + nl];
        a3 += c[mbase + m + 3] * fcwt[(size_t)(mbase + m + 3) * MD + n0 + nl];
    }
    pred[tid] = (a0 + a1) + (a2 + a3);
    __syncthreads();
    if (tid < 64)
        integ[(size_t)b * MD + n0 + tid] =
            pred[tid] + pred[tid + 64] + pred[tid + 128] + pred[tid + 192] + bias[n0 + tid];
}

// ---- Kernel E: LayerNorm ---------------------------------------------------
__global__ void k_ln(const float* __restrict__ integ, const float* __restrict__ gamma,
                     const float* __restrict__ beta, float* __restrict__ out) {
    __shared__ float red[8];
    const int tid = threadIdx.x, b = blockIdx.x;
    float v[4];
    #pragma unroll
    for (int k = 0; k < 4; ++k) v[k] = integ[(size_t)b * MD + tid + 256 * k];
    float s = v[0] + v[1] + v[2] + v[3];
    s = waveSum(s);
    const int wid = tid >> 6, lane = tid & 63;
    if (lane == 0) red[wid] = s;
    __syncthreads();
    const float mean = (red[0] + red[1] + red[2] + red[3]) * (1.f / MD);
    float q = 0.f;
    #pragma unroll
    for (int k = 0; k < 4; ++k) { float d = v[k] - mean; q += d * d; }
    q = waveSum(q);
    __syncthreads();
    if (lane == 0) red[4 + wid] = q;
    __syncthreads();
    const float var = (red[4] + red[5] + red[6] + red[7]) * (1.f / MD);
    const float rs = rsqrtf(var + LNEPS);
    #pragma unroll
    for (int k = 0; k < 4; ++k) {
        int i = tid + 256 * k;
        out[(size_t)b * MD + i] = (v[k] - mean) * rs * gamma[i] + beta[i];
    }
}

extern "C" void kernel_launch(void* const* d_in, const int* in_sizes, int n_in,
                              void* d_out, int out_size, void* d_ws, size_t ws_size,
                              hipStream_t stream) {
    const float* x     = (const float*)d_in[0];
    const float* wq    = (const float*)d_in[1];
    const float* wk    = (const float*)d_in[2];
    const float* wvp   = (const float*)d_in[3];
    const float* fcw   = (const float*)d_in[4];
    const float* fcb   = (const float*)d_in[5];
    const float* gamma = (const float*)d_in[6];
    const float* beta  = (const float*)d_in[7];
    const int*   idxp  = (const int*)d_in[8];
    float* out = (float*)d_out;

    const int sfull = in_sizes[0] / (B_ * MD);   // 4096

    float* q      = (float*)d_ws;
    float* wtil   = q      + (size_t)B_ * MD;
    float* scores = wtil   + (size_t)B_ * H_ * MD;
    float* concat = scores + (size_t)B_ * H_ * sfull;
    float* integ  = concat + (size_t)B_ * MD;
    float* fcwt   = integ  + (size_t)B_ * MD;

    hipLaunchKernelGGL(k_q,         dim3(4, 64),           dim3(256), 0, stream, x, wq, idxp, q, sfull);
    hipLaunchKernelGGL(k_wtil,      dim3(16, 32),          dim3(256), 0, stream, wk, q, wtil);
    hipLaunchKernelGGL(k_scores,    dim3(B_, (sfull + 511) / 512), dim3(256), 0, stream, x, wtil, idxp, scores, sfull);
    hipLaunchKernelGGL(k_transpose, dim3(32, 32),          dim3(256), 0, stream, fcw, fcwt);
    hipLaunchKernelGGL(k_attn,      dim3(H_, B_),          dim3(256), 0, stream, x, scores, wvp, idxp, concat, sfull);
    hipLaunchKernelGGL(k_fc,        dim3(64, 16),          dim3(256), 0, stream, concat, fcwt, fcb, integ);
    hipLaunchKernelGGL(k_ln,        dim3(B_),              dim3(256), 0, stream, integ, gamma, beta, out);
}